// Round 11
// baseline (404.212 us; speedup 1.0000x reference)
//
#include <hip/hip_runtime.h>
#include <hip/hip_bf16.h>

typedef unsigned short u16;
typedef float f32x4 __attribute__((ext_vector_type(4)));
typedef float f32x16 __attribute__((ext_vector_type(16)));
typedef __bf16 bf16x8 __attribute__((ext_vector_type(8)));
typedef u16 u16x4 __attribute__((ext_vector_type(4)));

#define NPIX 4096
#define CDIM 512
#define LOG2E 1.4426950408889634f

static __device__ __forceinline__ u16 f2bf(float f) {
  return __builtin_bit_cast(u16, (__bf16)f);
}
static __device__ __forceinline__ float bf2f(u16 u) {
  unsigned int v = ((unsigned int)u) << 16;
  return __builtin_bit_cast(float, v);
}
static __device__ __forceinline__ f32x16 zero16() {
  f32x16 z;
#pragma unroll
  for (int i = 0; i < 16; ++i) z[i] = 0.0f;
  return z;
}
static __device__ __forceinline__ f32x16 mfma16(bf16x8 a, bf16x8 b, f32x16 c) {
  return __builtin_amdgcn_mfma_f32_32x32x16_bf16(a, b, c, 0, 0, 0);
}

// ---------------------------------------------------------------------------
// Kernel 1: fused QKV projection (validated R1-R10, unchanged).
// ---------------------------------------------------------------------------
__global__ __launch_bounds__(640, 3) void proj_kernel(
    const float* __restrict__ x,
    const float* __restrict__ Wq, const float* __restrict__ bq,
    const float* __restrict__ Wk, const float* __restrict__ bk,
    const float* __restrict__ Wv, const float* __restrict__ bv,
    u16* __restrict__ qh, u16* __restrict__ ql,
    u16* __restrict__ kh, u16* __restrict__ vv)
{
  const int b = blockIdx.y;
  const int nbase = blockIdx.x * 64;
  const int tid = threadIdx.x;
  const int w = tid >> 6;
  const int lane = tid & 63;
  const int lhi = lane >> 5, llo = lane & 31;

  __shared__ float xs[2048];  // [32 k][64 n] fp32, 8 KB

  const float* xb = x + (size_t)b * CDIM * NPIX + nbase;

  const float* wrow[2];
#pragma unroll
  for (int rb = 0; rb < 2; ++rb) {
    int row = 64 * w + 32 * rb + llo;
    wrow[rb] = (row < 64) ? (Wq + (size_t)row * CDIM)
             : (row < 128) ? (Wk + (size_t)(row - 64) * CDIM)
                           : (Wv + (size_t)(row - 128) * CDIM);
  }

  f32x16 acc[2][2];
  acc[0][0] = zero16(); acc[0][1] = zero16();
  acc[1][0] = zero16(); acc[1][1] = zero16();

  for (int ks2 = 0; ks2 < 16; ++ks2) {
    __syncthreads();
    if (tid < 512) {
      int r = tid >> 4, ci = (tid & 15) << 2;
      *(f32x4*)&xs[r * 64 + ci] =
          *(const f32x4*)&xb[(size_t)(ks2 * 32 + r) * NPIX + ci];
    }
    __syncthreads();

#pragma unroll
    for (int kk = 0; kk < 2; ++kk) {
      const int ksoff = ks2 * 32 + kk * 16;
      bf16x8 af[2];
#pragma unroll
      for (int rb = 0; rb < 2; ++rb) {
        const float* wp = wrow[rb] + ksoff + 8 * lhi;
        f32x4 w0 = *(const f32x4*)(wp);
        f32x4 w1 = *(const f32x4*)(wp + 4);
#pragma unroll
        for (int j = 0; j < 4; ++j) { af[rb][j] = (__bf16)w0[j]; af[rb][4 + j] = (__bf16)w1[j]; }
      }
      bf16x8 bfr[2];
#pragma unroll
      for (int cb = 0; cb < 2; ++cb) {
        int n = 32 * cb + llo;
#pragma unroll
        for (int j = 0; j < 8; ++j)
          bfr[cb][j] = (__bf16)xs[(kk * 16 + 8 * lhi + j) * 64 + n];
      }
#pragma unroll
      for (int rb = 0; rb < 2; ++rb)
#pragma unroll
        for (int cb = 0; cb < 2; ++cb)
          acc[rb][cb] = mfma16(af[rb], bfr[cb], acc[rb][cb]);
    }
  }

  // Epilogue: C/D layout col = lane&31 (n), row = (r&3)+8*(r>>2)+4*lhi.
#pragma unroll
  for (int rb = 0; rb < 2; ++rb) {
#pragma unroll
    for (int cb = 0; cb < 2; ++cb) {
      int n = nbase + 32 * cb + llo;
#pragma unroll
      for (int gq = 0; gq < 4; ++gq) {
        int dr0 = 8 * gq + 4 * lhi;
        float vals[4];
#pragma unroll
        for (int jj = 0; jj < 4; ++jj) {
          int Mrow = 64 * w + 32 * rb + dr0 + jj;
          float bias = (Mrow < 64) ? bq[Mrow] : (Mrow < 128) ? bk[Mrow - 64] : bv[Mrow - 128];
          vals[jj] = acc[rb][cb][4 * gq + jj] + bias;
        }
        if (w == 0) {  // q: hi/lo pair, pre-scaled by log2(e)
          u16x4 hi, lo;
#pragma unroll
          for (int jj = 0; jj < 4; ++jj) {
            float vq = vals[jj] * LOG2E;
            hi[jj] = f2bf(vq);
            lo[jj] = f2bf(vq - bf2f(hi[jj]));
          }
          int o = 32 * rb + dr0;
          size_t off = ((size_t)b * NPIX + n) * 64 + o;
          *(u16x4*)(qh + off) = hi;
          *(u16x4*)(ql + off) = lo;
        } else if (w == 1) {  // k: hi only
          u16x4 hi;
#pragma unroll
          for (int jj = 0; jj < 4; ++jj) hi[jj] = f2bf(vals[jj]);
          int o = 32 * rb + dr0;
          size_t off = ((size_t)b * NPIX + n) * 64 + o;
          *(u16x4*)(kh + off) = hi;
        } else {
#pragma unroll
          for (int jj = 0; jj < 4; ++jj) {
            int c = 64 * w - 128 + 32 * rb + dr0 + jj;
            vv[((size_t)b * CDIM + c) * NPIX + n] = f2bf(vals[jj]);
          }
        }
      }
    }
  }
}

// ---------------------------------------------------------------------------
// Kernel 2: single-pass attention, 256-thread blocks for multi-block/CU.
// Residency ledger R2-R10: 512-thr blocks NEVER co-schedule (8 waves/CU at
// any LDS/VGPR); 1024-thr blocks get 16 waves but VGPR pinned 64 (spills);
// 256-thr blocks are the proven-stacking size (m97 GEMM: ~3 blocks/CU).
// Block = 4 waves = 32 q x 256 ch; grid 1024 = 128 qt x 4 batch x 2 cg.
// Per 128-key tile: wave w computes S quadrant (32q x 32k, kq=w; 8 MFMAs,
// q hi/lo x k hi) -> single 8KB swizzled P buffer; then PV on its 64-ch
// slice (8 ksteps x 2 accs = 16 MFMAs). launch_bounds(256,4) caps VGPR at
// 128 (demand ~120) -> 4 blocks/CU fits VGPR/LDS/threads exactly.
// ---------------------------------------------------------------------------

#define LOADK(T) do {                                                         \
  size_t koff_ = kbl + (size_t)(T) * (128 * 64);                              \
  _Pragma("unroll") for (int s_ = 0; s_ < 4; ++s_)                            \
    kf[s_] = *(const bf16x8*)(kh + koff_ + 16 * s_);                          \
} while (0)

#define S_PHASE() do {                                                        \
  f32x16 sacc_ = zero16();                                                    \
  _Pragma("unroll") for (int s_ = 0; s_ < 4; ++s_)                            \
    sacc_ = mfma16(qfh[s_], kf[s_], sacc_);                                   \
  _Pragma("unroll") for (int s_ = 0; s_ < 4; ++s_)                            \
    sacc_ = mfma16(qfl[s_], kf[s_], sacc_);                                   \
  _Pragma("unroll") for (int r_ = 0; r_ < 16; ++r_) {                         \
    float p_ = __builtin_amdgcn_exp2f(sacc_[r_]);                             \
    u16 pb_ = f2bf(p_);                                                       \
    l_part[r_] += bf2f(pb_);                                                  \
    int row_ = (r_ & 3) + 8 * (r_ >> 2) + 4 * lhi;                            \
    int byt_ = (row_ * 256 + (32 * w + llo) * 2) ^ ((row_ & 15) << 4);        \
    *(u16*)(Pb + byt_) = pb_;                                                 \
  }                                                                           \
} while (0)

#define PV_PHASE(T) do {                                                      \
  _Pragma("unroll") for (int s_ = 0; s_ < 8; ++s_) {                          \
    int by_ = (llo * 256 + (16 * s_ + 8 * lhi) * 2) ^ ((llo & 15) << 4);      \
    bf16x8 pa_ = *(const bf16x8*)(Pb + by_);                                  \
    bf16x8 vf0_ = *(const bf16x8*)(vv + vb0 + (size_t)(T) * 128 + 16 * s_);   \
    bf16x8 vf1_ = *(const bf16x8*)(vv + vb1 + (size_t)(T) * 128 + 16 * s_);   \
    acc0 = mfma16(pa_, vf0_, acc0);                                           \
    acc1 = mfma16(pa_, vf1_, acc1);                                           \
  }                                                                           \
} while (0)

__global__ __launch_bounds__(256, 4) void attn_kernel(
    const u16* __restrict__ qh, const u16* __restrict__ ql,
    const u16* __restrict__ kh, const u16* __restrict__ vv,
    const float* __restrict__ x, const float* __restrict__ gamma,
    float* __restrict__ out)
{
  const int bid = blockIdx.x;
  const int sw = ((bid & 7) << 7) | (bid >> 3);  // bijective, 1024 = 8*128
  const int batch = sw >> 8;          // 4
  const int cg = (sw >> 7) & 1;       // channel group (256 ch each)
  const int qbase = (sw & 127) * 32;  // 128 q-tiles of 32
  const int tid = threadIdx.x;
  const int w = tid >> 6;             // 4 waves; w = S key-quadrant & PV ch-slice
  const int lane = tid & 63;
  const int lhi = lane >> 5, llo = lane & 31;

  __shared__ alignas(16) char Pb[8192];   // [32 q][128 k] bf16, swizzled
  __shared__ float lred[32][4];
  __shared__ alignas(16) float rl_lds[32];

  // q fragments: rows 0..31 (same for all waves), hi/lo.
  bf16x8 qfh[4], qfl[4];
  {
    size_t qoff = ((size_t)batch * NPIX + qbase + llo) * 64 + 8 * lhi;
#pragma unroll
    for (int s = 0; s < 4; ++s) {
      qfh[s] = *(const bf16x8*)(qh + qoff + 16 * s);
      qfl[s] = *(const bf16x8*)(ql + qoff + 16 * s);
    }
  }

  const size_t kbl = ((size_t)batch * NPIX + 32 * w + llo) * 64 + 8 * lhi;
  const size_t vb0 =
      ((size_t)batch * CDIM + cg * 256 + 64 * w + llo) * NPIX + 8 * lhi;
  const size_t vb1 = vb0 + (size_t)32 * NPIX;

  f32x16 acc0 = zero16(), acc1 = zero16();
  float l_part[16];
#pragma unroll
  for (int r = 0; r < 16; ++r) l_part[r] = 0.0f;

  bf16x8 kf[4];  // single K fragment set, issue-early

  // Prologue: K(0) -> kf, S(0) -> Pb.
  LOADK(0);
  S_PHASE();
  __syncthreads();

  // Iter t: issue K(t+1), PV over P(t), barrier, S writes P(t+1), barrier.
  for (int t = 0; t < 31; ++t) {
    LOADK(t + 1);
    PV_PHASE(t);
    __syncthreads();
    S_PHASE();
    __syncthreads();
  }
  PV_PHASE(31);

  // Denominator: reduce l_part over the 32 key-lanes of each quadrant,
  // merge the 4 key-quadrant waves in LDS.
#pragma unroll
  for (int d = 1; d < 32; d <<= 1)
#pragma unroll
    for (int r = 0; r < 16; ++r) l_part[r] += __shfl_xor(l_part[r], d, 64);
  if (llo == 0) {
#pragma unroll
    for (int r = 0; r < 16; ++r) {
      int row = (r & 3) + 8 * (r >> 2) + 4 * lhi;
      lred[row][w] = l_part[r];
    }
  }
  __syncthreads();
  if (tid < 32)
    rl_lds[tid] = 1.0f / (lred[tid][0] + lred[tid][1] + lred[tid][2] + lred[tid][3]);
  __syncthreads();

  const float g = gamma[0];
#pragma unroll
  for (int cb = 0; cb < 2; ++cb) {
    const f32x16& a = cb ? acc1 : acc0;
    int c = cg * 256 + 64 * w + 32 * cb + llo;
#pragma unroll
    for (int gq = 0; gq < 4; ++gq) {
      int qrow = 8 * gq + 4 * lhi;
      size_t off = ((size_t)batch * CDIM + c) * NPIX + qbase + qrow;
      f32x4 xv = *(const f32x4*)(x + off);
      f32x4 rlv = *(const f32x4*)&rl_lds[qrow];
      f32x4 ov;
#pragma unroll
      for (int jj = 0; jj < 4; ++jj)
        ov[jj] = g * a[4 * gq + jj] * rlv[jj] + xv[jj];
      *(f32x4*)(out + off) = ov;
    }
  }
}

extern "C" void kernel_launch(void* const* d_in, const int* in_sizes, int n_in,
                              void* d_out, int out_size, void* d_ws, size_t ws_size,
                              hipStream_t stream) {
  (void)in_sizes; (void)n_in; (void)out_size; (void)ws_size;
  const float* x     = (const float*)d_in[0];
  const float* Wq    = (const float*)d_in[1];
  const float* bq    = (const float*)d_in[2];
  const float* Wk    = (const float*)d_in[3];
  const float* bk    = (const float*)d_in[4];
  const float* Wv    = (const float*)d_in[5];
  const float* bv    = (const float*)d_in[6];
  const float* gamma = (const float*)d_in[7];
  float* out = (float*)d_out;

  // Workspace layout (bytes): qh 0..2M, ql 2..4M, kh 4..6M, v 6..22M.
  char* ws = (char*)d_ws;
  u16* qh = (u16*)(ws);
  u16* ql = (u16*)(ws + (2u << 20));
  u16* kh = (u16*)(ws + (4u << 20));
  u16* vv = (u16*)(ws + (6u << 20));

  proj_kernel<<<dim3(64, 4), 640, 0, stream>>>(x, Wq, bq, Wk, bk, Wv, bv,
                                               qh, ql, kh, vv);
  attn_kernel<<<1024, 256, 0, stream>>>(qh, ql, kh, vv, x, gamma, out);
}

// Round 12
// 261.398 us; speedup vs baseline: 1.5463x; 1.5463x over previous
//
#include <hip/hip_runtime.h>
#include <hip/hip_bf16.h>

typedef unsigned short u16;
typedef float f32x4 __attribute__((ext_vector_type(4)));
typedef float f32x16 __attribute__((ext_vector_type(16)));
typedef __bf16 bf16x8 __attribute__((ext_vector_type(8)));
typedef _Float16 half8 __attribute__((ext_vector_type(8)));
typedef u16 u16x4 __attribute__((ext_vector_type(4)));
typedef u16 u16x8 __attribute__((ext_vector_type(8)));

#define NPIX 4096
#define CDIM 512
#define LOG2E 1.4426950408889634f

static __device__ __forceinline__ u16 f2bf(float f) {
  return __builtin_bit_cast(u16, (__bf16)f);
}
static __device__ __forceinline__ float bf2f(u16 u) {
  unsigned int v = ((unsigned int)u) << 16;
  return __builtin_bit_cast(float, v);
}
static __device__ __forceinline__ u16 f2h(float f) {
  return __builtin_bit_cast(u16, (_Float16)f);
}
static __device__ __forceinline__ f32x16 zero16() {
  f32x16 z;
#pragma unroll
  for (int i = 0; i < 16; ++i) z[i] = 0.0f;
  return z;
}
static __device__ __forceinline__ f32x16 mfma_bf(bf16x8 a, bf16x8 b, f32x16 c) {
  return __builtin_amdgcn_mfma_f32_32x32x16_bf16(a, b, c, 0, 0, 0);
}
static __device__ __forceinline__ f32x16 mfma_h(half8 a, half8 b, f32x16 c) {
  return __builtin_amdgcn_mfma_f32_32x32x16_f16(a, b, c, 0, 0, 0);
}

// ---------------------------------------------------------------------------
// Kernel 1: fused QKV projection (R1-R11 structure; MFMA switched to f16 for
// precision so q,k can be stored as SINGLE fp16: 2^-11 rounding vs bf16's
// 2^-8). q scaled by log2(e) (fp16), k fp16, v bf16 (range safety for PV).
// ---------------------------------------------------------------------------
__global__ __launch_bounds__(640, 3) void proj_kernel(
    const float* __restrict__ x,
    const float* __restrict__ Wq, const float* __restrict__ bq,
    const float* __restrict__ Wk, const float* __restrict__ bk,
    const float* __restrict__ Wv, const float* __restrict__ bv,
    u16* __restrict__ qh, u16* __restrict__ kh, u16* __restrict__ vv)
{
  const int b = blockIdx.y;
  const int nbase = blockIdx.x * 64;
  const int tid = threadIdx.x;
  const int w = tid >> 6;
  const int lane = tid & 63;
  const int lhi = lane >> 5, llo = lane & 31;

  __shared__ float xs[2048];  // [32 k][64 n] fp32, 8 KB

  const float* xb = x + (size_t)b * CDIM * NPIX + nbase;

  const float* wrow[2];
#pragma unroll
  for (int rb = 0; rb < 2; ++rb) {
    int row = 64 * w + 32 * rb + llo;
    wrow[rb] = (row < 64) ? (Wq + (size_t)row * CDIM)
             : (row < 128) ? (Wk + (size_t)(row - 64) * CDIM)
                           : (Wv + (size_t)(row - 128) * CDIM);
  }

  f32x16 acc[2][2];
  acc[0][0] = zero16(); acc[0][1] = zero16();
  acc[1][0] = zero16(); acc[1][1] = zero16();

  for (int ks2 = 0; ks2 < 16; ++ks2) {
    __syncthreads();
    if (tid < 512) {
      int r = tid >> 4, ci = (tid & 15) << 2;
      *(f32x4*)&xs[r * 64 + ci] =
          *(const f32x4*)&xb[(size_t)(ks2 * 32 + r) * NPIX + ci];
    }
    __syncthreads();

#pragma unroll
    for (int kk = 0; kk < 2; ++kk) {
      const int ksoff = ks2 * 32 + kk * 16;
      half8 af[2];
#pragma unroll
      for (int rb = 0; rb < 2; ++rb) {
        const float* wp = wrow[rb] + ksoff + 8 * lhi;
        f32x4 w0 = *(const f32x4*)(wp);
        f32x4 w1 = *(const f32x4*)(wp + 4);
#pragma unroll
        for (int j = 0; j < 4; ++j) {
          af[rb][j] = (_Float16)w0[j];
          af[rb][4 + j] = (_Float16)w1[j];
        }
      }
      half8 bfr[2];
#pragma unroll
      for (int cb = 0; cb < 2; ++cb) {
        int n = 32 * cb + llo;
#pragma unroll
        for (int j = 0; j < 8; ++j)
          bfr[cb][j] = (_Float16)xs[(kk * 16 + 8 * lhi + j) * 64 + n];
      }
#pragma unroll
      for (int rb = 0; rb < 2; ++rb)
#pragma unroll
        for (int cb = 0; cb < 2; ++cb)
          acc[rb][cb] = mfma_h(af[rb], bfr[cb], acc[rb][cb]);
    }
  }

  // Epilogue: C/D layout col = lane&31 (n), row = (r&3)+8*(r>>2)+4*lhi.
#pragma unroll
  for (int rb = 0; rb < 2; ++rb) {
#pragma unroll
    for (int cb = 0; cb < 2; ++cb) {
      int n = nbase + 32 * cb + llo;
#pragma unroll
      for (int gq = 0; gq < 4; ++gq) {
        int dr0 = 8 * gq + 4 * lhi;
        float vals[4];
#pragma unroll
        for (int jj = 0; jj < 4; ++jj) {
          int Mrow = 64 * w + 32 * rb + dr0 + jj;
          float bias = (Mrow < 64) ? bq[Mrow] : (Mrow < 128) ? bk[Mrow - 64] : bv[Mrow - 128];
          vals[jj] = acc[rb][cb][4 * gq + jj] + bias;
        }
        if (w == 0) {  // q: single fp16, pre-scaled by log2(e)
          u16x4 hq;
#pragma unroll
          for (int jj = 0; jj < 4; ++jj) hq[jj] = f2h(vals[jj] * LOG2E);
          size_t off = ((size_t)b * NPIX + n) * 64 + 32 * rb + dr0;
          *(u16x4*)(qh + off) = hq;
        } else if (w == 1) {  // k: single fp16
          u16x4 hk;
#pragma unroll
          for (int jj = 0; jj < 4; ++jj) hk[jj] = f2h(vals[jj]);
          size_t off = ((size_t)b * NPIX + n) * 64 + 32 * rb + dr0;
          *(u16x4*)(kh + off) = hk;
        } else {  // v: bf16 (P*V range needs bf16's exponent headroom via P)
#pragma unroll
          for (int jj = 0; jj < 4; ++jj) {
            int c = 64 * w - 128 + 32 * rb + dr0 + jj;
            vv[((size_t)b * CDIM + c) * NPIX + n] = f2bf(vals[jj]);
          }
        }
      }
    }
  }
}

// ---------------------------------------------------------------------------
// Kernel 2: single-pass attention with WAVE SPECIALIZATION, designed to FIT
// the allocator's 64-VGPR envelope (R7-R11: >64 never granted to non-512-thr
// blocks; 512-thr blocks never co-schedule).
// Block 1024 thr = 16 waves: w<8 PV-waves (32ch x 64q, acc 32 regs);
// w>=8 S-waves (one 32x32 S quadrant: kf 16 + l_part 16 + sacc 16, q read
// from swizzled LDS). Neither role exceeds ~62 regs -> no spills at 64.
// Grid 512 = 64qt x 4batch x 2chhalf (XCD-swizzled, R4-proven mapping).
// Per 128-key tile: S-waves build P(t+1) (f16 MFMA) into the spare P buffer
// while PV-waves consume P(t) (bf16 MFMA); 1 barrier/iter; K loads issued
// one phase ahead into kf.
// ---------------------------------------------------------------------------

#define LOADK(T) do {                                                         \
  size_t koff_ = kbl + (size_t)(T) * (128 * 64);                              \
  _Pragma("unroll") for (int s_ = 0; s_ < 4; ++s_)                            \
    kf[s_] = *(const half8*)(kh + koff_ + 16 * s_);                           \
} while (0)

#define S_PHASE(BUFB) do {                                                    \
  f32x16 sacc_ = zero16();                                                    \
  _Pragma("unroll") for (int s_ = 0; s_ < 4; ++s_) {                          \
    int qbyt_ = ((32 * rb_s + llo) * 128 + (16 * s_ + 8 * lhi) * 2)           \
                ^ ((llo & 7) << 4);                                           \
    half8 qf_ = *(const half8*)(Qs + qbyt_);                                  \
    sacc_ = mfma_h(qf_, kf[s_], sacc_);                                       \
  }                                                                           \
  _Pragma("unroll") for (int r_ = 0; r_ < 16; ++r_) {                         \
    float p_ = __builtin_amdgcn_exp2f(sacc_[r_]);                             \
    u16 pb_ = f2bf(p_);                                                       \
    l_part[r_] += bf2f(pb_);                                                  \
    int row_ = 32 * rb_s + (r_ & 3) + 8 * (r_ >> 2) + 4 * lhi;                \
    int byt_ = (row_ * 256 + (32 * kq + llo) * 2) ^ ((row_ & 15) << 4);       \
    *(u16*)((BUFB) + byt_) = pb_;                                             \
  }                                                                           \
} while (0)

#define PV_PHASE(BUFB, T) do {                                                \
  _Pragma("unroll") for (int s_ = 0; s_ < 8; ++s_) {                          \
    int by0_ = (llo * 256 + (16 * s_ + 8 * lhi) * 2) ^ ((llo & 15) << 4);     \
    bf16x8 pa0_ = *(const bf16x8*)((BUFB) + by0_);                            \
    bf16x8 pa1_ = *(const bf16x8*)((BUFB) + by0_ + 8192);                     \
    bf16x8 vf_ = *(const bf16x8*)(vv + vbase + (size_t)(T) * 128 + 16 * s_);  \
    acc0 = mfma_bf(pa0_, vf_, acc0);                                          \
    acc1 = mfma_bf(pa1_, vf_, acc1);                                          \
  }                                                                           \
} while (0)

__global__ __launch_bounds__(1024) void attn_kernel(
    const u16* __restrict__ qh, const u16* __restrict__ kh,
    const u16* __restrict__ vv,
    const float* __restrict__ x, const float* __restrict__ gamma,
    float* __restrict__ out)
{
  const int bid = blockIdx.x;
  const int sw = ((bid & 7) << 6) | (bid >> 3);  // bijective, 512 = 8*64
  const int batch = sw >> 7;          // XCD pair {2b,2b+1} -> batch b
  const int chhalf = (sw >> 6) & 1;   // XCD 2b+c -> channel half c
  const int qbase = (sw & 63) * 64;
  const int tid = threadIdx.x;
  const int w = tid >> 6;             // 16 waves: 0-7 PV, 8-15 S
  const int lane = tid & 63;
  const int lhi = lane >> 5, llo = lane & 31;
  const int swv = (w - 8) & 7;
  const int rb_s = swv & 1;           // S row half
  const int kq = swv >> 1;            // S key block (0..3)
  const bool isPV = (w < 8);

  __shared__ alignas(16) char Psm[32768];  // 2 x [64 q][128 k] bf16, swizzled
  __shared__ alignas(16) char Qs[8192];    // [64 q][64 d] fp16, swizzled
  __shared__ float lred[64][4];
  __shared__ alignas(16) float rl_lds[64];
  char* Pb0 = Psm;
  char* Pb1 = Psm + 16384;

  const size_t vbase =
      ((size_t)batch * CDIM + chhalf * 256 + 32 * w + llo) * NPIX + 8 * lhi;
  const size_t kbl = ((size_t)batch * NPIX + 32 * kq + llo) * 64 + 8 * lhi;

  f32x16 acc0 = zero16(), acc1 = zero16();
  float l_part[16];
#pragma unroll
  for (int r = 0; r < 16; ++r) l_part[r] = 0.0f;
  half8 kf[4];

  // Prologue: S-waves with kq==0 copy q (fp16) into swizzled LDS; all S-waves
  // issue K(0).
  if (!isPV) {
    if (kq == 0) {
#pragma unroll
      for (int j = 0; j < 4; ++j) {
        int c2 = lane + 64 * j;
        int row = 32 * rb_s + (c2 >> 3);
        int slot = c2 & 7;
        int byt = (row * 128 + slot * 16) ^ ((row & 7) << 4);
        *(u16x8*)(Qs + byt) =
            *(const u16x8*)(qh + ((size_t)batch * NPIX + qbase + row) * 64 + slot * 8);
      }
    }
    LOADK(0);
  }
  __syncthreads();  // q_lds ready
  if (!isPV) {
    S_PHASE(Pb0);   // S(0) with K(0)
    LOADK(1);
  }
  __syncthreads();

  // Main loop: phase t: PV consumes P(t); S builds P(t+1) and issues K(t+2).
  for (int tt = 0; tt < 15; ++tt) {
    const int t0 = 2 * tt;
    if (isPV) { PV_PHASE(Pb0, t0); }
    else      { S_PHASE(Pb1); LOADK(t0 + 2); }   // S(t0+1), K(t0+2)
    __syncthreads();
    const int t1 = t0 + 1;
    if (isPV) { PV_PHASE(Pb1, t1); }
    else      { S_PHASE(Pb0); if (t1 + 2 < 32) LOADK(t1 + 2); }  // S(t1+1)
    __syncthreads();
  }
  // t = 30: PV(B0,30) || S(31)->B1 (K31 already loaded).
  if (isPV) { PV_PHASE(Pb0, 30); }
  else      { S_PHASE(Pb1); }
  __syncthreads();
  // t = 31: PV(B1,31) || S-waves reduce l.
  if (isPV) {
    PV_PHASE(Pb1, 31);
  } else {
#pragma unroll
    for (int d = 1; d < 32; d <<= 1)
#pragma unroll
      for (int r = 0; r < 16; ++r) l_part[r] += __shfl_xor(l_part[r], d, 64);
    if (llo == 0) {
#pragma unroll
      for (int r = 0; r < 16; ++r) {
        int row = 32 * rb_s + (r & 3) + 8 * (r >> 2) + 4 * lhi;
        lred[row][kq] = l_part[r];
      }
    }
  }
  __syncthreads();
  if (tid < 64)
    rl_lds[tid] = 1.0f / (lred[tid][0] + lred[tid][1] + lred[tid][2] + lred[tid][3]);
  __syncthreads();

  // Epilogue (PV-waves): out = gamma * acc/l + x.
  if (isPV) {
    const float g = gamma[0];
    const int c = chhalf * 256 + 32 * w + llo;
#pragma unroll
    for (int ab = 0; ab < 2; ++ab) {
      const f32x16& a = ab ? acc1 : acc0;
#pragma unroll
      for (int gq = 0; gq < 4; ++gq) {
        int qrow = 32 * ab + 8 * gq + 4 * lhi;
        size_t off = ((size_t)batch * CDIM + c) * NPIX + qbase + qrow;
        f32x4 xv = *(const f32x4*)(x + off);
        f32x4 rlv = *(const f32x4*)&rl_lds[qrow];
        f32x4 ov;
#pragma unroll
        for (int jj = 0; jj < 4; ++jj)
          ov[jj] = g * a[4 * gq + jj] * rlv[jj] + xv[jj];
        *(f32x4*)(out + off) = ov;
      }
    }
  }
}

extern "C" void kernel_launch(void* const* d_in, const int* in_sizes, int n_in,
                              void* d_out, int out_size, void* d_ws, size_t ws_size,
                              hipStream_t stream) {
  (void)in_sizes; (void)n_in; (void)out_size; (void)ws_size;
  const float* x     = (const float*)d_in[0];
  const float* Wq    = (const float*)d_in[1];
  const float* bq    = (const float*)d_in[2];
  const float* Wk    = (const float*)d_in[3];
  const float* bk    = (const float*)d_in[4];
  const float* Wv    = (const float*)d_in[5];
  const float* bv    = (const float*)d_in[6];
  const float* gamma = (const float*)d_in[7];
  float* out = (float*)d_out;

  // Workspace layout (bytes): q fp16 0..2M, k fp16 2..4M, v bf16 4..20M.
  char* ws = (char*)d_ws;
  u16* qh = (u16*)(ws);
  u16* kh = (u16*)(ws + (2u << 20));
  u16* vv = (u16*)(ws + (4u << 20));

  proj_kernel<<<dim3(64, 4), 640, 0, stream>>>(x, Wq, bq, Wk, bk, Wv, bv,
                                               qh, kh, vv);
  attn_kernel<<<512, 1024, 0, stream>>>(qh, kh, vv, x, gamma, out);
}

// Round 13
// 225.048 us; speedup vs baseline: 1.7961x; 1.1615x over previous
//
#include <hip/hip_runtime.h>
#include <hip/hip_bf16.h>

typedef unsigned short u16;
typedef float f32x4 __attribute__((ext_vector_type(4)));
typedef float f32x16 __attribute__((ext_vector_type(16)));
typedef __bf16 bf16x8 __attribute__((ext_vector_type(8)));
typedef _Float16 half8 __attribute__((ext_vector_type(8)));
typedef u16 u16x4 __attribute__((ext_vector_type(4)));
typedef u16 u16x8 __attribute__((ext_vector_type(8)));

#define NPIX 4096
#define CDIM 512
#define LOG2E 1.4426950408889634f

static __device__ __forceinline__ u16 f2bf(float f) {
  return __builtin_bit_cast(u16, (__bf16)f);
}
static __device__ __forceinline__ float bf2f(u16 u) {
  unsigned int v = ((unsigned int)u) << 16;
  return __builtin_bit_cast(float, v);
}
static __device__ __forceinline__ u16 f2h(float f) {
  return __builtin_bit_cast(u16, (_Float16)f);
}
static __device__ __forceinline__ f32x16 zero16() {
  f32x16 z;
#pragma unroll
  for (int i = 0; i < 16; ++i) z[i] = 0.0f;
  return z;
}
static __device__ __forceinline__ f32x16 mfma_bf(bf16x8 a, bf16x8 b, f32x16 c) {
  return __builtin_amdgcn_mfma_f32_32x32x16_bf16(a, b, c, 0, 0, 0);
}
static __device__ __forceinline__ f32x16 mfma_h(half8 a, half8 b, f32x16 c) {
  return __builtin_amdgcn_mfma_f32_32x32x16_f16(a, b, c, 0, 0, 0);
}

// ---------------------------------------------------------------------------
// Kernel 1: fused QKV projection (R12 structure/numerics). NEW: k and v are
// written in MFMA-FRAGMENT order so attention's loads are wave-contiguous
// (64 lanes x 16B = 1KB segment = 8 txns, vs 32 txns for the old
// row-scattered layout — the R1-R12 hidden bottleneck).
//   kfrag[((b*32+T)*4+kq)*4+sf][lane=32*lh+(n&31)][j] = K[n][d], d=16sf+8lh+j
//   vfrag[(((b*2+ch)*8+cb)*32+T)*8+s][lane=32*lh+(c&31)][j] = V[c][n],
//     n = T*128+16s+8lh+j, cb = (c>>5)&7, ch = c>>8
// ---------------------------------------------------------------------------
__global__ __launch_bounds__(640, 3) void proj_kernel(
    const float* __restrict__ x,
    const float* __restrict__ Wq, const float* __restrict__ bq,
    const float* __restrict__ Wk, const float* __restrict__ bk,
    const float* __restrict__ Wv, const float* __restrict__ bv,
    u16* __restrict__ qh, u16* __restrict__ kh, u16* __restrict__ vv)
{
  const int b = blockIdx.y;
  const int nbase = blockIdx.x * 64;
  const int tid = threadIdx.x;
  const int w = tid >> 6;
  const int lane = tid & 63;
  const int lhi = lane >> 5, llo = lane & 31;

  __shared__ float xs[2048];  // [32 k][64 n] fp32, 8 KB

  const float* xb = x + (size_t)b * CDIM * NPIX + nbase;

  const float* wrow[2];
#pragma unroll
  for (int rb = 0; rb < 2; ++rb) {
    int row = 64 * w + 32 * rb + llo;
    wrow[rb] = (row < 64) ? (Wq + (size_t)row * CDIM)
             : (row < 128) ? (Wk + (size_t)(row - 64) * CDIM)
                           : (Wv + (size_t)(row - 128) * CDIM);
  }

  f32x16 acc[2][2];
  acc[0][0] = zero16(); acc[0][1] = zero16();
  acc[1][0] = zero16(); acc[1][1] = zero16();

  for (int ks2 = 0; ks2 < 16; ++ks2) {
    __syncthreads();
    if (tid < 512) {
      int r = tid >> 4, ci = (tid & 15) << 2;
      *(f32x4*)&xs[r * 64 + ci] =
          *(const f32x4*)&xb[(size_t)(ks2 * 32 + r) * NPIX + ci];
    }
    __syncthreads();

#pragma unroll
    for (int kk = 0; kk < 2; ++kk) {
      const int ksoff = ks2 * 32 + kk * 16;
      half8 af[2];
#pragma unroll
      for (int rb = 0; rb < 2; ++rb) {
        const float* wp = wrow[rb] + ksoff + 8 * lhi;
        f32x4 w0 = *(const f32x4*)(wp);
        f32x4 w1 = *(const f32x4*)(wp + 4);
#pragma unroll
        for (int j = 0; j < 4; ++j) {
          af[rb][j] = (_Float16)w0[j];
          af[rb][4 + j] = (_Float16)w1[j];
        }
      }
      half8 bfr[2];
#pragma unroll
      for (int cb = 0; cb < 2; ++cb) {
        int n = 32 * cb + llo;
#pragma unroll
        for (int j = 0; j < 8; ++j)
          bfr[cb][j] = (_Float16)xs[(kk * 16 + 8 * lhi + j) * 64 + n];
      }
#pragma unroll
      for (int rb = 0; rb < 2; ++rb)
#pragma unroll
        for (int cb = 0; cb < 2; ++cb)
          acc[rb][cb] = mfma_h(af[rb], bfr[cb], acc[rb][cb]);
    }
  }

  // Epilogue: C/D layout col = lane&31 (n), row = (r&3)+8*(r>>2)+4*lhi.
#pragma unroll
  for (int rb = 0; rb < 2; ++rb) {
#pragma unroll
    for (int cb = 0; cb < 2; ++cb) {
      int n = nbase + 32 * cb + llo;
#pragma unroll
      for (int gq = 0; gq < 4; ++gq) {
        int dr0 = 8 * gq + 4 * lhi;
        float vals[4];
#pragma unroll
        for (int jj = 0; jj < 4; ++jj) {
          int Mrow = 64 * w + 32 * rb + dr0 + jj;
          float bias = (Mrow < 64) ? bq[Mrow] : (Mrow < 128) ? bk[Mrow - 64] : bv[Mrow - 128];
          vals[jj] = acc[rb][cb][4 * gq + jj] + bias;
        }
        if (w == 0) {  // q: single fp16, pre-scaled by log2(e); [b][n][64] layout
          u16x4 hq;
#pragma unroll
          for (int jj = 0; jj < 4; ++jj) hq[jj] = f2h(vals[jj] * LOG2E);
          size_t off = ((size_t)b * NPIX + n) * 64 + 32 * rb + dr0;
          *(u16x4*)(qh + off) = hq;
        } else if (w == 1) {  // k: fp16, FRAGMENT layout
          u16x4 hk;
#pragma unroll
          for (int jj = 0; jj < 4; ++jj) hk[jj] = f2h(vals[jj]);
          // d = 32*rb + dr0 + jj; sf = d>>4 = 2rb + (gq>>1); lh = gq&1; j = 4lhi+jj
          int T = n >> 7, kq = (n >> 5) & 3, lf = n & 31;
          int sf = 2 * rb + (gq >> 1), lh = gq & 1;
          size_t F = (((size_t)b * 32 + T) * 4 + kq) * 4 + sf;
          *(u16x4*)(kh + F * 512 + (32 * lh + lf) * 8 + 4 * lhi) = hk;
        } else {  // v: bf16, FRAGMENT layout
          int T = n >> 7, s = (n >> 4) & 7, lh = (n >> 3) & 1, jn = n & 7;
#pragma unroll
          for (int jj = 0; jj < 4; ++jj) {
            int c = 64 * w - 128 + 32 * rb + dr0 + jj;
            size_t F = ((((size_t)b * 2 + (c >> 8)) * 8 + ((c >> 5) & 7)) * 32 + T) * 8 + s;
            vv[F * 512 + (32 * lh + (c & 31)) * 8 + jn] = f2bf(vals[jj]);
          }
        }
      }
    }
  }
}

// ---------------------------------------------------------------------------
// Kernel 2: wave-specialized single-pass attention (R12 structure, validated)
// with COALESCED K/V loads from the fragment layouts (1KB contiguous per
// wave-instruction) and a conflict-free slot-major Qs LDS layout.
// Block 1024 thr = 16 waves: w<8 PV (32ch x 64q), w>=8 S (32x32 quadrant).
// Grid 512 = 64qt x 4batch x 2chhalf, XCD-swizzled. 128-key tiles, P dbuf,
// 1 barrier/phase, K loads one phase ahead. All roles fit 64 VGPRs.
// ---------------------------------------------------------------------------

#define LOADK(T) do {                                                         \
  size_t koff_ = ((((size_t)batch * 32 + (size_t)(T)) * 4 + kq) * 4) * 512    \
                 + (size_t)lane * 8;                                          \
  _Pragma("unroll") for (int s_ = 0; s_ < 4; ++s_)                            \
    kf[s_] = *(const half8*)(kh + koff_ + s_ * 512);                          \
} while (0)

#define S_PHASE(BUFB) do {                                                    \
  f32x16 sacc_ = zero16();                                                    \
  _Pragma("unroll") for (int s_ = 0; s_ < 4; ++s_) {                          \
    int qbyt_ = (2 * s_ + lhi) * 1024 + (32 * rb_s + llo) * 16;               \
    half8 qf_ = *(const half8*)(Qs + qbyt_);                                  \
    sacc_ = mfma_h(qf_, kf[s_], sacc_);                                       \
  }                                                                           \
  _Pragma("unroll") for (int r_ = 0; r_ < 16; ++r_) {                         \
    float p_ = __builtin_amdgcn_exp2f(sacc_[r_]);                             \
    u16 pb_ = f2bf(p_);                                                       \
    l_part[r_] += bf2f(pb_);                                                  \
    int row_ = 32 * rb_s + (r_ & 3) + 8 * (r_ >> 2) + 4 * lhi;                \
    int byt_ = (row_ * 256 + (32 * kq + llo) * 2) ^ ((row_ & 15) << 4);       \
    *(u16*)((BUFB) + byt_) = pb_;                                             \
  }                                                                           \
} while (0)

#define PV_PHASE(BUFB, T) do {                                                \
  size_t vF0_ = ((((size_t)batch * 2 + chhalf) * 8 + w) * 32                  \
                 + (size_t)(T)) * 8;                                          \
  _Pragma("unroll") for (int s_ = 0; s_ < 8; ++s_) {                          \
    int by0_ = (llo * 256 + (16 * s_ + 8 * lhi) * 2) ^ ((llo & 15) << 4);     \
    bf16x8 pa0_ = *(const bf16x8*)((BUFB) + by0_);                            \
    bf16x8 pa1_ = *(const bf16x8*)((BUFB) + by0_ + 8192);                     \
    bf16x8 vf_ = *(const bf16x8*)(vv + (vF0_ + s_) * 512 + lane * 8);         \
    acc0 = mfma_bf(pa0_, vf_, acc0);                                          \
    acc1 = mfma_bf(pa1_, vf_, acc1);                                          \
  }                                                                           \
} while (0)

__global__ __launch_bounds__(1024) void attn_kernel(
    const u16* __restrict__ qh, const u16* __restrict__ kh,
    const u16* __restrict__ vv,
    const float* __restrict__ x, const float* __restrict__ gamma,
    float* __restrict__ out)
{
  const int bid = blockIdx.x;
  const int sw = ((bid & 7) << 6) | (bid >> 3);  // bijective, 512 = 8*64
  const int batch = sw >> 7;          // XCD pair {2b,2b+1} -> batch b
  const int chhalf = (sw >> 6) & 1;   // XCD 2b+c -> channel half c
  const int qbase = (sw & 63) * 64;
  const int tid = threadIdx.x;
  const int w = tid >> 6;             // 16 waves: 0-7 PV, 8-15 S
  const int lane = tid & 63;
  const int lhi = lane >> 5, llo = lane & 31;
  const int swv = (w - 8) & 7;
  const int rb_s = swv & 1;           // S row half
  const int kq = swv >> 1;            // S key block (0..3)
  const bool isPV = (w < 8);

  __shared__ alignas(16) char Psm[32768];  // 2 x [64 q][128 k] bf16, swizzled
  __shared__ alignas(16) char Qs[8192];    // [d8 0..7][64 q] x 16B, slot-major
  __shared__ float lred[64][4];
  __shared__ alignas(16) float rl_lds[64];
  char* Pb0 = Psm;
  char* Pb1 = Psm + 16384;

  f32x16 acc0 = zero16(), acc1 = zero16();
  float l_part[16];
#pragma unroll
  for (int r = 0; r < 16; ++r) l_part[r] = 0.0f;
  half8 kf[4];

  // Prologue: S-waves with kq==0 fill Qs (slot-major, conflict-free reads);
  // all S-waves issue K(0).
  if (!isPV) {
    if (kq == 0) {
#pragma unroll
      for (int j = 0; j < 4; ++j) {
        int idx = lane + 64 * j;            // 0..255
        int d8 = idx & 7;
        int row = 32 * rb_s + (idx >> 3);   // this wave's 32 q-rows
        *(u16x8*)(Qs + d8 * 1024 + row * 16) =
            *(const u16x8*)(qh + ((size_t)batch * NPIX + qbase + row) * 64 + d8 * 8);
      }
    }
    LOADK(0);
  }
  __syncthreads();  // Qs ready
  if (!isPV) {
    S_PHASE(Pb0);   // S(0) with K(0)
    LOADK(1);
  }
  __syncthreads();

  // Main loop: phase t: PV consumes P(t); S builds P(t+1) and issues K(t+2).
  for (int tt = 0; tt < 15; ++tt) {
    const int t0 = 2 * tt;
    if (isPV) { PV_PHASE(Pb0, t0); }
    else      { S_PHASE(Pb1); LOADK(t0 + 2); }
    __syncthreads();
    const int t1 = t0 + 1;
    if (isPV) { PV_PHASE(Pb1, t1); }
    else      { S_PHASE(Pb0); if (t1 + 2 < 32) LOADK(t1 + 2); }
    __syncthreads();
  }
  // t = 30: PV(B0,30) || S(31)->B1.
  if (isPV) { PV_PHASE(Pb0, 30); }
  else      { S_PHASE(Pb1); }
  __syncthreads();
  // t = 31: PV(B1,31) || S-waves reduce l.
  if (isPV) {
    PV_PHASE(Pb1, 31);
  } else {
#pragma unroll
    for (int d = 1; d < 32; d <<= 1)
#pragma unroll
      for (int r = 0; r < 16; ++r) l_part[r] += __shfl_xor(l_part[r], d, 64);
    if (llo == 0) {
#pragma unroll
      for (int r = 0; r < 16; ++r) {
        int row = 32 * rb_s + (r & 3) + 8 * (r >> 2) + 4 * lhi;
        lred[row][kq] = l_part[r];
      }
    }
  }
  __syncthreads();
  if (tid < 64)
    rl_lds[tid] = 1.0f / (lred[tid][0] + lred[tid][1] + lred[tid][2] + lred[tid][3]);
  __syncthreads();

  // Epilogue (PV-waves): out = gamma * acc/l + x.
  if (isPV) {
    const float g = gamma[0];
    const int c = chhalf * 256 + 32 * w + llo;
#pragma unroll
    for (int ab = 0; ab < 2; ++ab) {
      const f32x16& a = ab ? acc1 : acc0;
#pragma unroll
      for (int gq = 0; gq < 4; ++gq) {
        int qrow = 32 * ab + 8 * gq + 4 * lhi;
        size_t off = ((size_t)batch * CDIM + c) * NPIX + qbase + qrow;
        f32x4 xv = *(const f32x4*)(x + off);
        f32x4 rlv = *(const f32x4*)&rl_lds[qrow];
        f32x4 ov;
#pragma unroll
        for (int jj = 0; jj < 4; ++jj)
          ov[jj] = g * a[4 * gq + jj] * rlv[jj] + xv[jj];
        *(f32x4*)(out + off) = ov;
      }
    }
  }
}

extern "C" void kernel_launch(void* const* d_in, const int* in_sizes, int n_in,
                              void* d_out, int out_size, void* d_ws, size_t ws_size,
                              hipStream_t stream) {
  (void)in_sizes; (void)n_in; (void)out_size; (void)ws_size;
  const float* x     = (const float*)d_in[0];
  const float* Wq    = (const float*)d_in[1];
  const float* bq    = (const float*)d_in[2];
  const float* Wk    = (const float*)d_in[3];
  const float* bk    = (const float*)d_in[4];
  const float* Wv    = (const float*)d_in[5];
  const float* bv    = (const float*)d_in[6];
  const float* gamma = (const float*)d_in[7];
  float* out = (float*)d_out;

  // Workspace layout (bytes): q fp16 0..2M, k-frag fp16 2..4M, v-frag bf16 4..20M.
  char* ws = (char*)d_ws;
  u16* qh = (u16*)(ws);
  u16* kh = (u16*)(ws + (2u << 20));
  u16* vv = (u16*)(ws + (4u << 20));

  proj_kernel<<<dim3(64, 4), 640, 0, stream>>>(x, Wq, bq, Wk, bk, Wv, bv,
                                               qh, kh, vv);
  attn_kernel<<<512, 1024, 0, stream>>>(qh, kh, vv, x, gamma, out);
}

// Round 15
// 193.922 us; speedup vs baseline: 2.0844x; 1.1605x over previous
//
#include <hip/hip_runtime.h>
#include <hip/hip_bf16.h>

typedef unsigned short u16;
typedef float f32x4 __attribute__((ext_vector_type(4)));
typedef float f32x16 __attribute__((ext_vector_type(16)));
typedef __bf16 bf16x8 __attribute__((ext_vector_type(8)));
typedef _Float16 half8 __attribute__((ext_vector_type(8)));
typedef u16 u16x4 __attribute__((ext_vector_type(4)));
typedef u16 u16x8 __attribute__((ext_vector_type(8)));

#define NPIX 4096
#define CDIM 512
#define LOG2E 1.4426950408889634f

static __device__ __forceinline__ u16 f2bf(float f) {
  return __builtin_bit_cast(u16, (__bf16)f);
}
static __device__ __forceinline__ float bf2f(u16 u) {
  unsigned int v = ((unsigned int)u) << 16;
  return __builtin_bit_cast(float, v);
}
static __device__ __forceinline__ u16 f2h(float f) {
  return __builtin_bit_cast(u16, (_Float16)f);
}
static __device__ __forceinline__ f32x16 zero16() {
  f32x16 z;
#pragma unroll
  for (int i = 0; i < 16; ++i) z[i] = 0.0f;
  return z;
}
static __device__ __forceinline__ f32x16 mfma_bf(bf16x8 a, bf16x8 b, f32x16 c) {
  return __builtin_amdgcn_mfma_f32_32x32x16_bf16(a, b, c, 0, 0, 0);
}
static __device__ __forceinline__ f32x16 mfma_h32(half8 a, half8 b, f32x16 c) {
  return __builtin_amdgcn_mfma_f32_32x32x16_f16(a, b, c, 0, 0, 0);
}

// ---------------------------------------------------------------------------
// Kernel 1: fused QKV projection — byte-identical to R13 (validated).
// Fragment layouts:
//   kfrag F = ((b*32+T128)*4+kq128)*4+sf
//   vfrag F = (((b*2+ch)*8+cb)*32+T128)*8+s128
// ---------------------------------------------------------------------------
__global__ __launch_bounds__(640, 3) void proj_kernel(
    const float* __restrict__ x,
    const float* __restrict__ Wq, const float* __restrict__ bq,
    const float* __restrict__ Wk, const float* __restrict__ bk,
    const float* __restrict__ Wv, const float* __restrict__ bv,
    u16* __restrict__ qh, u16* __restrict__ kh, u16* __restrict__ vv)
{
  const int b = blockIdx.y;
  const int nbase = blockIdx.x * 64;
  const int tid = threadIdx.x;
  const int w = tid >> 6;
  const int lane = tid & 63;
  const int lhi = lane >> 5, llo = lane & 31;

  __shared__ float xs[2048];  // [32 k][64 n] fp32, 8 KB

  const float* xb = x + (size_t)b * CDIM * NPIX + nbase;

  const float* wrow[2];
#pragma unroll
  for (int rb = 0; rb < 2; ++rb) {
    int row = 64 * w + 32 * rb + llo;
    wrow[rb] = (row < 64) ? (Wq + (size_t)row * CDIM)
             : (row < 128) ? (Wk + (size_t)(row - 64) * CDIM)
                           : (Wv + (size_t)(row - 128) * CDIM);
  }

  f32x16 acc[2][2];
  acc[0][0] = zero16(); acc[0][1] = zero16();
  acc[1][0] = zero16(); acc[1][1] = zero16();

  for (int ks2 = 0; ks2 < 16; ++ks2) {
    __syncthreads();
    if (tid < 512) {
      int r = tid >> 4, ci = (tid & 15) << 2;
      *(f32x4*)&xs[r * 64 + ci] =
          *(const f32x4*)&xb[(size_t)(ks2 * 32 + r) * NPIX + ci];
    }
    __syncthreads();

#pragma unroll
    for (int kk = 0; kk < 2; ++kk) {
      const int ksoff = ks2 * 32 + kk * 16;
      half8 af[2];
#pragma unroll
      for (int rb = 0; rb < 2; ++rb) {
        const float* wp = wrow[rb] + ksoff + 8 * lhi;
        f32x4 w0 = *(const f32x4*)(wp);
        f32x4 w1 = *(const f32x4*)(wp + 4);
#pragma unroll
        for (int j = 0; j < 4; ++j) {
          af[rb][j] = (_Float16)w0[j];
          af[rb][4 + j] = (_Float16)w1[j];
        }
      }
      half8 bfr[2];
#pragma unroll
      for (int cb = 0; cb < 2; ++cb) {
        int n = 32 * cb + llo;
#pragma unroll
        for (int j = 0; j < 8; ++j)
          bfr[cb][j] = (_Float16)xs[(kk * 16 + 8 * lhi + j) * 64 + n];
      }
#pragma unroll
      for (int rb = 0; rb < 2; ++rb)
#pragma unroll
        for (int cb = 0; cb < 2; ++cb)
          acc[rb][cb] = mfma_h32(af[rb], bfr[cb], acc[rb][cb]);
    }
  }

  // Epilogue: C/D layout col = lane&31 (n), row = (r&3)+8*(r>>2)+4*lhi.
#pragma unroll
  for (int rb = 0; rb < 2; ++rb) {
#pragma unroll
    for (int cb = 0; cb < 2; ++cb) {
      int n = nbase + 32 * cb + llo;
#pragma unroll
      for (int gq = 0; gq < 4; ++gq) {
        int dr0 = 8 * gq + 4 * lhi;
        float vals[4];
#pragma unroll
        for (int jj = 0; jj < 4; ++jj) {
          int Mrow = 64 * w + 32 * rb + dr0 + jj;
          float bias = (Mrow < 64) ? bq[Mrow] : (Mrow < 128) ? bk[Mrow - 64] : bv[Mrow - 128];
          vals[jj] = acc[rb][cb][4 * gq + jj] + bias;
        }
        if (w == 0) {  // q: single fp16, pre-scaled by log2(e); [b][n][64]
          u16x4 hq;
#pragma unroll
          for (int jj = 0; jj < 4; ++jj) hq[jj] = f2h(vals[jj] * LOG2E);
          size_t off = ((size_t)b * NPIX + n) * 64 + 32 * rb + dr0;
          *(u16x4*)(qh + off) = hq;
        } else if (w == 1) {  // k: fp16, fragment layout
          u16x4 hk;
#pragma unroll
          for (int jj = 0; jj < 4; ++jj) hk[jj] = f2h(vals[jj]);
          int T = n >> 7, kq = (n >> 5) & 3, lf = n & 31;
          int sf = 2 * rb + (gq >> 1), lh = gq & 1;
          size_t F = (((size_t)b * 32 + T) * 4 + kq) * 4 + sf;
          *(u16x4*)(kh + F * 512 + (32 * lh + lf) * 8 + 4 * lhi) = hk;
        } else {  // v: bf16, fragment layout
          int T = n >> 7, s = (n >> 4) & 7, lh = (n >> 3) & 1, jn = n & 7;
#pragma unroll
          for (int jj = 0; jj < 4; ++jj) {
            int c = 64 * w - 128 + 32 * rb + dr0 + jj;
            size_t F = ((((size_t)b * 2 + (c >> 8)) * 8 + ((c >> 5) & 7)) * 32 + T) * 8 + s;
            vv[F * 512 + (32 * lh + (c & 31)) * 8 + jn] = f2bf(vals[jj]);
          }
        }
      }
    }
  }
}

// ---------------------------------------------------------------------------
// Kernel 2: 3-role wave-specialized attention (PV / S / V-stager).
// R13 post-mortem: phase wall ~6300cyc vs 1280 MFMA — PV's in-loop V loads
// expose L2 latency (64-VGPR cap forbids register pipelining). Fix: 4 stager
// waves copy V(t+1) frags global->LDS during phase t (coalesced 1KB loads +
// linear ds_write; barrier drain guarantees completion); PV reads V via
// conflict-free ds_read_b128. 64-key tiles: LDS = P dbuf 16K + V dbuf 64K +
// Qs 8K + red ~1K = ~90K. Roles: w0-7 PV (acc 32 regs), w8-11 S (quadrant
// rb_s x kq of 64q x 64k), w12-15 stagers (~30 regs). All fit 64 VGPR.
// ---------------------------------------------------------------------------

#define LOADK(T) do {                                                         \
  size_t F_ = (((size_t)batch * 32 + ((T) >> 1)) * 4                          \
               + (2 * ((T) & 1) + kq)) * 4;                                   \
  const u16* kp_ = kh + F_ * 512 + (size_t)lane * 8;                          \
  _Pragma("unroll") for (int s_ = 0; s_ < 4; ++s_)                            \
    kf[s_] = *(const half8*)(kp_ + s_ * 512);                                 \
} while (0)

#define S_PHASE(PB) do {                                                      \
  f32x16 sacc_ = zero16();                                                    \
  _Pragma("unroll") for (int s_ = 0; s_ < 4; ++s_) {                          \
    half8 qf_ = *(const half8*)(Qs + (2 * s_ + lhi) * 1024                    \
                                + (32 * rb_s + llo) * 16);                    \
    sacc_ = mfma_h32(qf_, kf[s_], sacc_);                                     \
  }                                                                           \
  _Pragma("unroll") for (int r_ = 0; r_ < 16; ++r_) {                         \
    float p_ = __builtin_amdgcn_exp2f(sacc_[r_]);                             \
    u16 pb_ = f2bf(p_);                                                       \
    l_part[r_] += bf2f(pb_);                                                  \
    int row_ = 32 * rb_s + (r_ & 3) + 8 * (r_ >> 2) + 4 * lhi;                \
    int byt_ = (row_ * 128 + (32 * kq + llo) * 2) ^ ((row_ & 7) << 4);        \
    *(u16*)((PB) + byt_) = pb_;                                               \
  }                                                                           \
} while (0)

#define PV_PHASE(PB, VB) do {                                                 \
  _Pragma("unroll") for (int s_ = 0; s_ < 4; ++s_) {                          \
    int by0_ = (llo * 128 + (16 * s_ + 8 * lhi) * 2) ^ ((llo & 7) << 4);      \
    bf16x8 pa0_ = *(const bf16x8*)((PB) + by0_);                              \
    bf16x8 pa1_ = *(const bf16x8*)((PB) + by0_ + 4096);                       \
    bf16x8 vf_ = *(const bf16x8*)((VB) + (w * 4 + s_) * 1024 + lane * 16);    \
    acc0 = mfma_bf(pa0_, vf_, acc0);                                          \
    acc1 = mfma_bf(pa1_, vf_, acc1);                                          \
  }                                                                           \
} while (0)

// Stager: copy 8 V fragments (cb = 2sv, 2sv+1; s = 0..3) of tile T into VB.
#define STAGE(T, VB) do {                                                     \
  size_t sb_ = ((size_t)(bc8 + 2 * sv) * 256 + ((T) >> 1) * 8                 \
                + 4 * ((T) & 1)) * 512 + (size_t)lane * 8;                    \
  char* d0_ = (VB) + (2 * sv) * 4096 + lane * 16;                             \
  bf16x8 r0_ = *(const bf16x8*)(vv + sb_);                                    \
  bf16x8 r1_ = *(const bf16x8*)(vv + sb_ + 512);                              \
  bf16x8 r2_ = *(const bf16x8*)(vv + sb_ + 1024);                             \
  bf16x8 r3_ = *(const bf16x8*)(vv + sb_ + 1536);                             \
  *(bf16x8*)(d0_)        = r0_;                                               \
  *(bf16x8*)(d0_ + 1024) = r1_;                                               \
  *(bf16x8*)(d0_ + 2048) = r2_;                                               \
  *(bf16x8*)(d0_ + 3072) = r3_;                                               \
  r0_ = *(const bf16x8*)(vv + sb_ + 131072);                                  \
  r1_ = *(const bf16x8*)(vv + sb_ + 131072 + 512);                            \
  r2_ = *(const bf16x8*)(vv + sb_ + 131072 + 1024);                           \
  r3_ = *(const bf16x8*)(vv + sb_ + 131072 + 1536);                           \
  *(bf16x8*)(d0_ + 4096)        = r0_;                                        \
  *(bf16x8*)(d0_ + 4096 + 1024) = r1_;                                        \
  *(bf16x8*)(d0_ + 4096 + 2048) = r2_;                                        \
  *(bf16x8*)(d0_ + 4096 + 3072) = r3_;                                        \
} while (0)

__global__ __launch_bounds__(1024) void attn_kernel(
    const u16* __restrict__ qh, const u16* __restrict__ kh,
    const u16* __restrict__ vv,
    const float* __restrict__ x, const float* __restrict__ gamma,
    float* __restrict__ out)
{
  const int bid = blockIdx.x;
  const int sw = ((bid & 7) << 6) | (bid >> 3);  // bijective, 512 = 8*64
  const int batch = sw >> 7;
  const int chhalf = (sw >> 6) & 1;
  const int qbase = (sw & 63) * 64;
  const int tid = threadIdx.x;
  const int w = tid >> 6;             // 0-7 PV, 8-11 S, 12-15 stager
  const int lane = tid & 63;
  const int lhi = lane >> 5, llo = lane & 31;
  const int swv = (w - 8) & 3;
  const int rb_s = swv & 1;           // S row half
  const int kq = swv >> 1;            // S key block (0..1) within 64-key tile
  const int sv = (w - 12) & 3;        // stager index
  const int bc8 = (batch * 2 + chhalf) * 8;

  __shared__ alignas(16) char Psm[16384];   // 2 x [64 q][64 k] bf16, swizzled
  __shared__ alignas(16) char Vsm[65536];   // 2 x 32 frags x 1 KB, linear
  __shared__ alignas(16) char Qs[8192];     // [d8][64 q] x 16 B, slot-major
  __shared__ float lred[64][2];
  __shared__ alignas(16) float rl_lds[64];
  char* Pb0 = Psm;
  char* Pb1 = Psm + 8192;
  char* Vb0 = Vsm;
  char* Vb1 = Vsm + 32768;

  f32x16 acc0 = zero16(), acc1 = zero16();
  float l_part[16];
#pragma unroll
  for (int r = 0; r < 16; ++r) l_part[r] = 0.0f;
  half8 kf[4];

  // Prologue 1: S waves fill Qs + load K(0); stagers stage V(0) -> Vb0.
  if (w >= 8 && w < 12) {
#pragma unroll
    for (int j = 0; j < 2; ++j) {
      int idx = swv * 128 + j * 64 + lane;   // 0..511
      int d8 = idx & 7, row = idx >> 3;
      *(u16x8*)(Qs + d8 * 1024 + row * 16) =
          *(const u16x8*)(qh + ((size_t)batch * NPIX + qbase + row) * 64 + d8 * 8);
    }
    LOADK(0);
  } else if (w >= 12) {
    STAGE(0, Vb0);
  }
  __syncthreads();
  // Prologue 2: S(0) -> Pb0; load K(1).
  if (w >= 8 && w < 12) { S_PHASE(Pb0); LOADK(1); }
  __syncthreads();

  // Main loop: 64 key-tiles, 1 barrier/phase.
  // Even phase t0: PV(t0) from Pb0/Vb0; S(t0+1)->Pb1; stage V(t0+1)->Vb1.
  for (int tt = 0; tt < 32; ++tt) {
    const int t0 = 2 * tt;
    if (w < 8) {
      PV_PHASE(Pb0, Vb0);
    } else if (w < 12) {
      S_PHASE(Pb1);
      if (t0 + 2 < 64) LOADK(t0 + 2);
    } else {
      STAGE(t0 + 1, Vb1);
    }
    __syncthreads();
    const int t1 = t0 + 1;
    if (w < 8) {
      PV_PHASE(Pb1, Vb1);
    } else if (w < 12) {
      if (t1 < 63) {
        S_PHASE(Pb0);
        if (t1 + 2 < 64) LOADK(t1 + 2);
      } else {
        // Final phase: reduce l over the 32 key-lanes, publish to lred.
#pragma unroll
        for (int d = 1; d < 32; d <<= 1)
#pragma unroll
          for (int r = 0; r < 16; ++r) l_part[r] += __shfl_xor(l_part[r], d, 64);
        if (llo == 0) {
#pragma unroll
          for (int r = 0; r < 16; ++r) {
            int row = 32 * rb_s + (r & 3) + 8 * (r >> 2) + 4 * lhi;
            lred[row][kq] = l_part[r];
          }
        }
      }
    } else {
      if (t1 < 63) STAGE(t1 + 1, Vb0);
    }
    __syncthreads();
  }

  if (tid < 64) rl_lds[tid] = 1.0f / (lred[tid][0] + lred[tid][1]);
  __syncthreads();

  // Epilogue (PV waves): out = gamma * acc/l + x.
  if (w < 8) {
    const float g = gamma[0];
    const int c = chhalf * 256 + 32 * w + llo;
#pragma unroll
    for (int ab = 0; ab < 2; ++ab) {
      const f32x16& a = ab ? acc1 : acc0;
#pragma unroll
      for (int gq = 0; gq < 4; ++gq) {
        int qrow = 32 * ab + 8 * gq + 4 * lhi;
        size_t off = ((size_t)batch * CDIM + c) * NPIX + qbase + qrow;
        f32x4 xv = *(const f32x4*)(x + off);
        f32x4 rlv = *(const f32x4*)&rl_lds[qrow];
        f32x4 ov;
#pragma unroll
        for (int jj = 0; jj < 4; ++jj)
          ov[jj] = g * a[4 * gq + jj] * rlv[jj] + xv[jj];
        *(f32x4*)(out + off) = ov;
      }
    }
  }
}

extern "C" void kernel_launch(void* const* d_in, const int* in_sizes, int n_in,
                              void* d_out, int out_size, void* d_ws, size_t ws_size,
                              hipStream_t stream) {
  (void)in_sizes; (void)n_in; (void)out_size; (void)ws_size;
  const float* x     = (const float*)d_in[0];
  const float* Wq    = (const float*)d_in[1];
  const float* bq    = (const float*)d_in[2];
  const float* Wk    = (const float*)d_in[3];
  const float* bk    = (const float*)d_in[4];
  const float* Wv    = (const float*)d_in[5];
  const float* bv    = (const float*)d_in[6];
  const float* gamma = (const float*)d_in[7];
  float* out = (float*)d_out;

  // Workspace layout (bytes): q fp16 0..2M, k-frag fp16 2..4M, v-frag bf16 4..20M.
  char* ws = (char*)d_ws;
  u16* qh = (u16*)(ws);
  u16* kh = (u16*)(ws + (2u << 20));
  u16* vv = (u16*)(ws + (4u << 20));

  proj_kernel<<<dim3(64, 4), 640, 0, stream>>>(x, Wq, bq, Wk, bk, Wv, bv,
                                               qh, kh, vv);
  attn_kernel<<<512, 1024, 0, stream>>>(qh, kh, vv, x, gamma, out);
}